// Round 1
// baseline (362.383 us; speedup 1.0000x reference)
//
#include <hip/hip_runtime.h>

// FragAttention: masked prefix-sum along s.
//   x: (S, B, D) f32, src_mask: (B, S) int (True=pad)
//   out: (B, G, 2D) f32, G = S-1
//   left[b,g,d]  = sum_{s<=g} x[s,b,d]*valid[b,s]
//   right[b,g,d] = total[b,d] - left[b,g,d]
#define SS 128
#define BB 512
#define DD 512
#define GG 127

__global__ __launch_bounds__(256) void frag_prefix_kernel(
    const float* __restrict__ x, const int* __restrict__ mask,
    float* __restrict__ out) {
  const int b = blockIdx.x >> 1;              // 2 blocks per batch row
  const int d = ((blockIdx.x & 1) << 8) + threadIdx.x;  // 256 d's per block

  __shared__ float valid[SS];
  if (threadIdx.x < SS) {
    valid[threadIdx.x] = mask[b * SS + threadIdx.x] ? 0.0f : 1.0f;
  }
  __syncthreads();

  // x[s, b, d] : stride B*D between s; lanes are consecutive d -> coalesced.
  const float* xp = x + (size_t)b * DD + d;
  float v[SS];
#pragma unroll
  for (int s = 0; s < SS; ++s) {
    v[s] = xp[(size_t)s * (BB * DD)] * valid[s];
  }

  float total = 0.0f;
#pragma unroll
  for (int s = 0; s < SS; ++s) total += v[s];

  // out[b, g, c] with c = d (left) or D + d (right)
  float* outp = out + (size_t)b * (GG * 2 * DD) + d;
  float run = 0.0f;
#pragma unroll
  for (int g = 0; g < GG; ++g) {
    run += v[g];
    outp[(size_t)g * (2 * DD)] = run;
    outp[(size_t)g * (2 * DD) + DD] = total - run;
  }
}

extern "C" void kernel_launch(void* const* d_in, const int* in_sizes, int n_in,
                              void* d_out, int out_size, void* d_ws, size_t ws_size,
                              hipStream_t stream) {
  const float* x = (const float*)d_in[0];
  const int* mask = (const int*)d_in[1];
  float* out = (float*)d_out;
  // Grid: 2 blocks per b (256 d's each) -> 1024 blocks x 256 threads.
  frag_prefix_kernel<<<dim3(BB * 2), dim3(256), 0, stream>>>(x, mask, out);
}

// Round 2
// 359.007 us; speedup vs baseline: 1.0094x; 1.0094x over previous
//
#include <hip/hip_runtime.h>

// FragAttention: masked prefix-sum along s.
//   x: (S, B, D) f32, src_mask: (B, S) int (True=pad)
//   out: (B, G, 2D) f32, G = S-1
//   left[b,g,d]  = sum_{s<=g} x[s,b,d]*valid[b,s]
//   right[b,g,d] = total[b,d] - left[b,g,d]
//
// Layout: block = 512 threads = 8 waves, covers one b and 256 consecutive d's
// (64 float4 columns). Wave j owns s-chunk [16j, 16j+16). Per-thread state is
// v[16] float4 (64 VGPRs) -- no spill. Chunk partial sums exchanged via LDS
// to produce per-thread prefix offset + column total. All global accesses are
// 64 lanes x 16 B contiguous.
#define SS 128
#define BB 512
#define DD 512
#define GG 127
#define CS 16   // s-values per thread
#define NC 8    // chunks (= waves per block)

__global__ __launch_bounds__(512) void frag_prefix_kernel(
    const float* __restrict__ x, const int* __restrict__ mask,
    float* __restrict__ out) {
  const int tid = threadIdx.x;
  const int b = blockIdx.x >> 1;
  const int dblk = (blockIdx.x & 1) << 8;  // 0 or 256 (floats)
  const int col = tid & 63;                // float4 column within block
  const int j = tid >> 6;                  // s-chunk / wave id

  __shared__ float valid[SS];
  __shared__ float4 part[NC][64];

  if (tid < SS) valid[tid] = mask[b * SS + tid] ? 0.0f : 1.0f;
  __syncthreads();

  // x as float4: s-stride = B*D/4 float4's.
  const size_t sstride = (size_t)BB * DD / 4;
  const float4* xq = (const float4*)x +
                     (size_t)(j * CS) * sstride +
                     ((size_t)b * DD + dblk) / 4 + col;

  float4 v[CS];
#pragma unroll
  for (int i = 0; i < CS; ++i) {
    float4 t = xq[(size_t)i * sstride];
    float m = valid[j * CS + i];
    v[i].x = t.x * m; v[i].y = t.y * m; v[i].z = t.z * m; v[i].w = t.w * m;
  }

  float4 psum = v[0];
#pragma unroll
  for (int i = 1; i < CS; ++i) {
    psum.x += v[i].x; psum.y += v[i].y; psum.z += v[i].z; psum.w += v[i].w;
  }
  part[j][col] = psum;
  __syncthreads();

  float4 offset = make_float4(0.f, 0.f, 0.f, 0.f);
  float4 total = make_float4(0.f, 0.f, 0.f, 0.f);
#pragma unroll
  for (int jj = 0; jj < NC; ++jj) {
    float4 p = part[jj][col];
    total.x += p.x; total.y += p.y; total.z += p.z; total.w += p.w;
    if (jj < j) { offset.x += p.x; offset.y += p.y; offset.z += p.z; offset.w += p.w; }
  }

  // out[b, g, c]: g-stride = 2*D/4 = 256 float4's; right half at +D/4 = +128.
  float4* op = (float4*)out + ((size_t)b * GG * 2 * DD + dblk) / 4 + col;
  float4 run = offset;
#pragma unroll
  for (int i = 0; i < CS; ++i) {
    run.x += v[i].x; run.y += v[i].y; run.z += v[i].z; run.w += v[i].w;
    const int g = j * CS + i;
    if (g < GG) {  // wave-uniform: only wave 7's last iteration skips
      op[(size_t)g * (2 * DD / 4)] = run;
      float4 r;
      r.x = total.x - run.x; r.y = total.y - run.y;
      r.z = total.z - run.z; r.w = total.w - run.w;
      op[(size_t)g * (2 * DD / 4) + DD / 4] = r;
    }
  }
}

extern "C" void kernel_launch(void* const* d_in, const int* in_sizes, int n_in,
                              void* d_out, int out_size, void* d_ws, size_t ws_size,
                              hipStream_t stream) {
  const float* x = (const float*)d_in[0];
  const int* mask = (const int*)d_in[1];
  float* out = (float*)d_out;
  // 2 blocks per b (256 floats of d each) -> 1024 blocks x 512 threads.
  frag_prefix_kernel<<<dim3(BB * 2), dim3(512), 0, stream>>>(x, mask, out);
}